// Round 3
// baseline (170.518 us; speedup 1.0000x reference)
//
#include <hip/hip_runtime.h>
#include <math.h>

#define HIDDEN 64
#define TOTAL  4417   // 5*64 + 1 + 64*64
#define TSTEPS 64

// coefficient layout per batch row:
//   w_ih  [0,   64)
//   w_hh  [64,  4160)   row-major [k][j]: 64 + k*64 + j
//   b_ih  [4160,4224)
//   b_hh  [4224,4288)
//   fc_w  [4288,4352)
//   fc_b  [4352,4353)
//   h0    [4353,4417)

typedef float f4 __attribute__((ext_vector_type(4)));

__global__ __launch_bounds__(64, 4)
void rnn_fused_kernel(const float* __restrict__ coeff,
                      const float* __restrict__ xin,
                      float* __restrict__ out)
{
    const int b    = blockIdx.x;
    const int lane = threadIdx.x;              // 0..63, one wave per block

    const float* __restrict__ c = coeff + (size_t)b * TOTAL;

    __shared__ __align__(16) float hsh[HIDDEN];   // h vector (single-wave block)

    // ---- per-lane parameters ----
    const float wih  = c[lane];
    const float bias = c[4160 + lane] + c[4224 + lane];
    const float fcw  = c[4288 + lane];
    const float fcb  = c[4352];
    const float h0   = c[4353 + lane];
    const float xv   = xin[(size_t)b * TSTEPS + lane];  // lane t holds x[b][t]

    // ---- W row: lane k owns w_hh[b][k][*] in 64 NAMED registers ----
    // R1/R2 showed the compiler refuses to keep a W[64] array resident
    // (VGPR_Count 44/40 -> scratch / per-step refetch). asm-volatile loads
    // into named scalars cannot be rematerialized, duplicated, or sunk.
    // Scalar dword loads because the row base is only 4-byte aligned
    // (TOTAL*4 = 17668 B is not a multiple of 16).
    const float* wrow = c + HIDDEN + (size_t)lane * HIDDEN;

#define WLOAD(n, offs) float w##n; \
    asm volatile("global_load_dword %0, %1, off offset:" offs \
                 : "=v"(w##n) : "v"(wrow));
    WLOAD(0,"0")     WLOAD(1,"4")     WLOAD(2,"8")     WLOAD(3,"12")
    WLOAD(4,"16")    WLOAD(5,"20")    WLOAD(6,"24")    WLOAD(7,"28")
    WLOAD(8,"32")    WLOAD(9,"36")    WLOAD(10,"40")   WLOAD(11,"44")
    WLOAD(12,"48")   WLOAD(13,"52")   WLOAD(14,"56")   WLOAD(15,"60")
    WLOAD(16,"64")   WLOAD(17,"68")   WLOAD(18,"72")   WLOAD(19,"76")
    WLOAD(20,"80")   WLOAD(21,"84")   WLOAD(22,"88")   WLOAD(23,"92")
    WLOAD(24,"96")   WLOAD(25,"100")  WLOAD(26,"104")  WLOAD(27,"108")
    WLOAD(28,"112")  WLOAD(29,"116")  WLOAD(30,"120")  WLOAD(31,"124")
    WLOAD(32,"128")  WLOAD(33,"132")  WLOAD(34,"136")  WLOAD(35,"140")
    WLOAD(36,"144")  WLOAD(37,"148")  WLOAD(38,"152")  WLOAD(39,"156")
    WLOAD(40,"160")  WLOAD(41,"164")  WLOAD(42,"168")  WLOAD(43,"172")
    WLOAD(44,"176")  WLOAD(45,"180")  WLOAD(46,"184")  WLOAD(47,"188")
    WLOAD(48,"192")  WLOAD(49,"196")  WLOAD(50,"200")  WLOAD(51,"204")
    WLOAD(52,"208")  WLOAD(53,"212")  WLOAD(54,"216")  WLOAD(55,"220")
    WLOAD(56,"224")  WLOAD(57,"228")  WLOAD(58,"232")  WLOAD(59,"236")
    WLOAD(60,"240")  WLOAD(61,"244")  WLOAD(62,"248")  WLOAD(63,"252")
#undef WLOAD
    asm volatile("s_waitcnt vmcnt(0)" ::: "memory");
    __builtin_amdgcn_sched_barrier(0);   // rule #18: no register uses may hoist past the wait

    hsh[lane] = h0;
    __builtin_amdgcn_wave_barrier();     // single-wave block: DS ops in-order, compile-time fence only

    float hn = h0;
    const f4* hp = (const f4*)hsh;

    #pragma unroll 1
    for (int t = 0; t < TSTEPS; ++t) {
        // uniform broadcast of x[b][t]
        const float xt = __int_as_float(
            __builtin_amdgcn_readlane(__float_as_int(xv), t));
        float a0 = fmaf(xt, wih, bias);
        float a1 = 0.0f, a2 = 0.0f, a3 = 0.0f;

        // acc += sum_j h[j] * W[lane][j]; h broadcast-read from LDS
        // (uniform address across lanes = conflict-free). 4 accumulators
        // break the fma dependence chain.
#define ACC4(q, wa, wb, wc, wd) { const f4 hv = hp[q]; \
        a0 = fmaf(hv.x, wa, a0); a1 = fmaf(hv.y, wb, a1); \
        a2 = fmaf(hv.z, wc, a2); a3 = fmaf(hv.w, wd, a3); }
        ACC4(0,  w0,  w1,  w2,  w3)
        ACC4(1,  w4,  w5,  w6,  w7)
        ACC4(2,  w8,  w9,  w10, w11)
        ACC4(3,  w12, w13, w14, w15)
        ACC4(4,  w16, w17, w18, w19)
        ACC4(5,  w20, w21, w22, w23)
        ACC4(6,  w24, w25, w26, w27)
        ACC4(7,  w28, w29, w30, w31)
        ACC4(8,  w32, w33, w34, w35)
        ACC4(9,  w36, w37, w38, w39)
        ACC4(10, w40, w41, w42, w43)
        ACC4(11, w44, w45, w46, w47)
        ACC4(12, w48, w49, w50, w51)
        ACC4(13, w52, w53, w54, w55)
        ACC4(14, w56, w57, w58, w59)
        ACC4(15, w60, w61, w62, w63)
#undef ACC4
        const float acc = (a0 + a1) + (a2 + a3);

        // tanh(a) = 1 - 2/(e^{2a}+1); robust at +-inf
        const float e = __expf(acc + acc);
        hn = 1.0f - 2.0f * __builtin_amdgcn_rcpf(e + 1.0f);

        __builtin_amdgcn_wave_barrier();  // all reads of old h precede the write
        hsh[lane] = hn;
        __builtin_amdgcn_wave_barrier();  // write precedes next-iter reads
    }

    // ---- readout: pred = sum_k h[k]*fc_w[k] + fc_b ----
    float p = hn * fcw;
    #pragma unroll
    for (int off = 32; off > 0; off >>= 1)
        p += __shfl_xor(p, off, 64);

    if (lane == 0) out[b] = p + fcb;
}

extern "C" void kernel_launch(void* const* d_in, const int* in_sizes, int n_in,
                              void* d_out, int out_size, void* d_ws, size_t ws_size,
                              hipStream_t stream)
{
    const float* coeff = (const float*)d_in[0];
    const float* xin   = (const float*)d_in[1];
    float* out         = (float*)d_out;

    const int B = in_sizes[0] / TOTAL;   // 16384

    rnn_fused_kernel<<<B, HIDDEN, 0, stream>>>(coeff, xin, out);
}